// Round 8
// baseline (7064.598 us; speedup 1.0000x reference)
//
#include <hip/hip_runtime.h>

#define BATCH 64
#define SEQ   512
#define INPD  128
#define HID   256
#define G4    1024   // 4*HID
#define HSL   36     // h slice stride in floats -> conflict-free b128 reads
#define NB    4      // batches per block

// 64 blocks x 512 threads. Block = (part p = bid>>4, group G = bid&15) and
// owns batches b0..b0+3 (b0 = 4G) for hidden units [64p, 64p+64).
// bid = G + 16p keeps a batch's 4 part-blocks on one XCD (bid%8 == G%8).
// Thread: CG = tid>>3 (hidden unit), S = tid&7 (k-slice: 32 h-rows + 16 x-rows).
// Weights in regs, SHARED across the 4 batches: wh[32][4], wi[16][4] = 192 f32.
// Per iteration (4 phases, one batch-step each, 1 barrier per phase):
//   phase i: [spin-check pre-issued poll for batch i -> h into LDS] barrier
//            XPART (x regs loaded last phase) + 32-row h-matvec (b128 LDS)
//            issue x loads + poll load for NEXT phase
//            DPP allreduce over 8 S-lanes -> bias -> branch-free DPP cell
//            update; S==1 lane stores: exch (tag st+1), hbuf-next, out.
// Exchange for batch i stored at iter st is consumed at iter st+1 phase i
// (a full iteration later) with its poll load pre-issued one phase earlier
// -> cross-block RTT fully hidden behind the other 3 batches' compute.
// Tag-carrying 64-bit relaxed agent-scope atomics, parity double-buffered.

template<int CTRL>
__device__ __forceinline__ float dppf(float v) {
    return __int_as_float(__builtin_amdgcn_update_dpp(
        0, __float_as_int(v), CTRL, 0xF, 0xF, true));
}
#define DPP_XOR1 0xB1   // quad_perm [1,0,3,2]
#define DPP_XOR2 0x4E   // quad_perm [2,3,0,1]
#define DPP_HMIR 0x141  // row_half_mirror

#define HROW(h, r) { \
    a0 = fmaf(h, wh[(r)*4+0], a0); a1 = fmaf(h, wh[(r)*4+1], a1); \
    a2 = fmaf(h, wh[(r)*4+2], a2); a3 = fmaf(h, wh[(r)*4+3], a3); }

#define XROW(h, r) { \
    a0 = fmaf(h, wi[(r)*4+0], a0); a1 = fmaf(h, wi[(r)*4+1], a1); \
    a2 = fmaf(h, wi[(r)*4+2], a2); a3 = fmaf(h, wi[(r)*4+3], a3); }

#define XPART_ALL { \
    a0 = nx0.x * wi[0]; a1 = nx0.x * wi[1]; a2 = nx0.x * wi[2]; a3 = nx0.x * wi[3]; \
    XROW(nx0.y, 1)  XROW(nx0.z, 2)  XROW(nx0.w, 3) \
    XROW(nx1.x, 4)  XROW(nx1.y, 5)  XROW(nx1.z, 6)  XROW(nx1.w, 7) \
    XROW(nx2.x, 8)  XROW(nx2.y, 9)  XROW(nx2.z, 10) XROW(nx2.w, 11) \
    XROW(nx3.x, 12) XROW(nx3.y, 13) XROW(nx3.z, 14) XROW(nx3.w, 15) }

__global__ __launch_bounds__(512, 2)
void ChaoticLSTM_kernel(const float* __restrict__ x,  const float* __restrict__ Wi,
                        const float* __restrict__ Wh, const float* __restrict__ Bb,
                        float* __restrict__ out, unsigned long long* __restrict__ exch)
{
    const int bid  = blockIdx.x;               // 64 blocks
    const int part = bid >> 4;                 // 0..3
    const int G    = bid & 15;                 // batch group
    const int b0   = G * NB;
    const int tid  = threadIdx.x;
    const int CG   = tid >> 3;                 // hidden unit 0..63
    const int S    = tid & 7;                  // k-slice
    const int jglob = part * 64 + CG;

    __shared__ __align__(16) float hbuf[NB][2][8 * HSL];

    // ---- weights into registers: all 4 gate columns of unit CG ----
    float wh[128];   // [r<32][g<4] : h-row S*32+r, col g*256+jglob
    float wi[64];    // [r<16][g<4] : x-row S*16+r
    {
#pragma unroll
        for (int r = 0; r < 32; ++r) {
            const float* p = Wh + (size_t)(S * 32 + r) * G4 + jglob;
            wh[r*4+0] = p[0]; wh[r*4+1] = p[256]; wh[r*4+2] = p[512]; wh[r*4+3] = p[768];
        }
#pragma unroll
        for (int r = 0; r < 16; ++r) {
            const float* p = Wi + (size_t)(S * 16 + r) * G4 + jglob;
            wi[r*4+0] = p[0]; wi[r*4+1] = p[256]; wi[r*4+2] = p[512]; wi[r*4+3] = p[768];
        }
    }
    const float bb0 = Bb[jglob],       bb1 = Bb[256 + jglob];
    const float bb2 = Bb[512 + jglob], bb3 = Bb[768 + jglob];

    unsigned long long* __restrict__ exb = exch + (size_t)b0 * 512;
    const float* __restrict__ xb = x + (size_t)b0 * SEQ * INPD + S * 16;

    // ---- roles ----
    const bool is_own  = (S == 1);
    const bool is_poll = (S >= 2 && S <= 4);
    int pidx = 0;
    if (is_poll) {
        int pl = CG * 3 + (S - 2);             // 0..191
        pidx = (((part + 1 + (pl >> 6)) & 3) << 6) + (pl & 63);
    }

    // ---- init ----
    for (int k = tid; k < NB * 2 * 8 * HSL; k += 512) ((float*)hbuf)[k] = 0.f;
    if (tid < 64) {
#pragma unroll
        for (int i = 0; i < NB; ++i) {
            __hip_atomic_store(&exb[i*512 + part*64 + tid],       0ull, __ATOMIC_RELAXED, __HIP_MEMORY_SCOPE_AGENT);
            __hip_atomic_store(&exb[i*512 + 256 + part*64 + tid], 0ull, __ATOMIC_RELAXED, __HIP_MEMORY_SCOPE_AGENT);
        }
    }
    float csA[NB] = {0.f, 0.f, 0.f, 0.f};

    // prologue x load: batch 0, step 0
    float4 nx0 = *(const float4*)(xb);
    float4 nx1 = *(const float4*)(xb + 4);
    float4 nx2 = *(const float4*)(xb + 8);
    float4 nx3 = *(const float4*)(xb + 12);
    unsigned long long vp = 0;
    __syncthreads();

    for (int st = 0; st < SEQ; ++st) {
#pragma unroll
        for (int i = 0; i < NB; ++i) {
            // ---- finish pre-issued poll for (batch i, tag st) ----
            if (st > 0 && is_poll) {
                unsigned long long* sp = exb + i*512 + (st & 1) * 256;
                unsigned long long v = vp;
                while ((unsigned)(v >> 32) != (unsigned)st)
                    v = __hip_atomic_load(&sp[pidx], __ATOMIC_RELAXED, __HIP_MEMORY_SCOPE_AGENT);
                hbuf[i][st & 1][(pidx >> 5) * HSL + (pidx & 31)] = __uint_as_float((unsigned)v);
            }
            __syncthreads();

            // ---- matvec: x-part then 32 h-rows (conflict-free b128) ----
            float a0, a1, a2, a3;
            XPART_ALL;
            {
                const float* hb = &hbuf[i][st & 1][S * HSL];
                float4 hv;
                hv = *(const float4*)(hb);      HROW(hv.x, 0)  HROW(hv.y, 1)  HROW(hv.z, 2)  HROW(hv.w, 3)
                hv = *(const float4*)(hb + 4);  HROW(hv.x, 4)  HROW(hv.y, 5)  HROW(hv.z, 6)  HROW(hv.w, 7)
                hv = *(const float4*)(hb + 8);  HROW(hv.x, 8)  HROW(hv.y, 9)  HROW(hv.z, 10) HROW(hv.w, 11)
                hv = *(const float4*)(hb + 12); HROW(hv.x, 12) HROW(hv.y, 13) HROW(hv.z, 14) HROW(hv.w, 15)
                hv = *(const float4*)(hb + 16); HROW(hv.x, 16) HROW(hv.y, 17) HROW(hv.z, 18) HROW(hv.w, 19)
                hv = *(const float4*)(hb + 20); HROW(hv.x, 20) HROW(hv.y, 21) HROW(hv.z, 22) HROW(hv.w, 23)
                hv = *(const float4*)(hb + 24); HROW(hv.x, 24) HROW(hv.y, 25) HROW(hv.z, 26) HROW(hv.w, 27)
                hv = *(const float4*)(hb + 28); HROW(hv.x, 28) HROW(hv.y, 29) HROW(hv.z, 30) HROW(hv.w, 31)
            }

            // ---- issue next phase's x loads + poll load (hide latency) ----
            {
                const int ni  = (i + 1) & 3;
                const int nst = (i == 3) ? st + 1 : st;
                if (nst < SEQ) {
                    const float* xp = xb + (size_t)ni * SEQ * INPD + (size_t)nst * INPD;
                    nx0 = *(const float4*)(xp);
                    nx1 = *(const float4*)(xp + 4);
                    nx2 = *(const float4*)(xp + 8);
                    nx3 = *(const float4*)(xp + 12);
                    if (is_poll && nst > 0) {
                        unsigned long long* sp = exb + ni*512 + (nst & 1) * 256;
                        vp = __hip_atomic_load(&sp[pidx], __ATOMIC_RELAXED, __HIP_MEMORY_SCOPE_AGENT);
                    }
                }
            }

            // ---- DPP allreduce over 8 S-lanes + bias ----
            a0 += dppf<DPP_XOR1>(a0); a1 += dppf<DPP_XOR1>(a1); a2 += dppf<DPP_XOR1>(a2); a3 += dppf<DPP_XOR1>(a3);
            a0 += dppf<DPP_XOR2>(a0); a1 += dppf<DPP_XOR2>(a1); a2 += dppf<DPP_XOR2>(a2); a3 += dppf<DPP_XOR2>(a3);
            a0 += dppf<DPP_HMIR>(a0); a1 += dppf<DPP_HMIR>(a1); a2 += dppf<DPP_HMIR>(a2); a3 += dppf<DPP_HMIR>(a3);
            a0 += bb0; a1 += bb1; a2 += bb2; a3 += bb3;

            // ---- branch-free cell update (valid on S==1 lane) ----
            const int r = S & 3;               // 0:i 1:f 2:g 3:o
            float xs = (r & 1) ? ((r & 2) ? a3 : a1) : ((r & 2) ? a2 : a0);
            float kk = (r == 2) ? 2.f : 1.f;
            float e  = __expf(-kk * xs);
            float z  = __builtin_amdgcn_rcpf(1.f + e);
            z = fmaf(z, kk, 1.f - kk);         // g-role: 2*sig(2x)-1 = tanh(x)
            float zg = dppf<DPP_XOR2>(z);      // r1 lane <- sig(o); r0 <- tanh(g)
            float p  = z * zg;                 // r0: i*g
            float pp = dppf<DPP_XOR1>(p);      // r1 <- i*g
            float cn = fmaf(z, csA[i], pp);    // r1: f*c + i*g
            float e2 = __expf(-2.f * cn);
            float tc = fmaf(__builtin_amdgcn_rcpf(1.f + e2), 2.f, -1.f);
            float hn = tc * zg;                // r1: o * tanh(c')
            csA[i] = cn;

            // ---- owner stores ----
            if (is_own) {
                const unsigned tag = (unsigned)(st + 1);
                out[((size_t)(b0 + i) * SEQ + st) * HID + jglob] = hn;
                hbuf[i][(st + 1) & 1][(jglob >> 5) * HSL + (jglob & 31)] = hn;
                if (st + 1 < SEQ) {
                    unsigned long long w = ((unsigned long long)tag << 32)
                                         | (unsigned long long)__float_as_uint(hn);
                    __hip_atomic_store(&exb[i*512 + ((st + 1) & 1) * 256 + jglob], w,
                                       __ATOMIC_RELAXED, __HIP_MEMORY_SCOPE_AGENT);
                } else {
                    size_t base = (size_t)BATCH * SEQ * HID;
                    out[base + (size_t)(b0 + i) * HID + jglob] = hn;
                    out[base + (size_t)BATCH * HID + (size_t)(b0 + i) * HID + jglob] = cn;
                }
            }
        }
    }
}

extern "C" void kernel_launch(void* const* d_in, const int* in_sizes, int n_in,
                              void* d_out, int out_size, void* d_ws, size_t ws_size,
                              hipStream_t stream) {
    const float* x  = (const float*)d_in[0];
    const float* Wi = (const float*)d_in[1];
    const float* Wh = (const float*)d_in[2];
    const float* B  = (const float*)d_in[3];
    float* out = (float*)d_out;
    unsigned long long* exch = (unsigned long long*)d_ws;   // 64*4*512*8 = 1 MB? -> 64 batches*512*8 = 256 KB

    ChaoticLSTM_kernel<<<dim3(64), dim3(512), 0, stream>>>(x, Wi, Wh, B, out, exch);
}

// Round 9
// 1395.211 us; speedup vs baseline: 5.0635x; 5.0635x over previous
//
#include <hip/hip_runtime.h>

#define BATCH 64
#define SEQ   512
#define INPD  128
#define HID   256
#define G4    1024   // 4*HID

// 256 blocks x 512 threads. Block (batch b, part) owns 64 hidden units.
// Thread: CG = tid>>3 (unit), S = tid&7 (k-slice). Each thread holds all 4
// gate columns of unit (part*64+CG): wh[4 chunks][8 rows][4 gates] +
// wi[16][4] = 192 f32 in regs. Chunk q covers h-rows of part (part+q)&3.
// Per step: chunk0 = x-part + OWN part (no wait) -> chunks 1..3 consume
// remote parts via LDS flag handoff (acquire/release), published by poller
// waves 7,6,5 which poll partner exchange words at step start. Cell update
// via quad-DPP roles (as R7). ONE barrier per step (parity buffer reuse).
// Cross-block exchange: step-tagged 64-bit relaxed agent-scope atomics,
// parity double-buffered; partners share an XCD (bid%8 = b>>3).

template<int CTRL>
__device__ __forceinline__ float dppf(float v) {
    return __int_as_float(__builtin_amdgcn_update_dpp(
        0, __float_as_int(v), CTRL, 0xF, 0xF, true));
}
#define DPP_XOR1 0xB1   // quad_perm [1,0,3,2]
#define DPP_XOR2 0x4E   // quad_perm [2,3,0,1]
#define DPP_HMIR 0x141  // row_half_mirror

#define HROW4(base, h) { \
    a0 = fmaf(h, wh[(base)+0], a0); a1 = fmaf(h, wh[(base)+1], a1); \
    a2 = fmaf(h, wh[(base)+2], a2); a3 = fmaf(h, wh[(base)+3], a3); }

#define HCHUNK(q, h0, h1) { \
    HROW4((q)*32+ 0, h0.x) HROW4((q)*32+ 4, h0.y) HROW4((q)*32+ 8, h0.z) HROW4((q)*32+12, h0.w) \
    HROW4((q)*32+16, h1.x) HROW4((q)*32+20, h1.y) HROW4((q)*32+24, h1.z) HROW4((q)*32+28, h1.w) }

#define XROW(r, h) { \
    a0 = fmaf(h, wi[(r)*4+0], a0); a1 = fmaf(h, wi[(r)*4+1], a1); \
    a2 = fmaf(h, wi[(r)*4+2], a2); a3 = fmaf(h, wi[(r)*4+3], a3); }

#define XPART_ALL { \
    a0 = nx0.x*wi[0]; a1 = nx0.x*wi[1]; a2 = nx0.x*wi[2]; a3 = nx0.x*wi[3]; \
    XROW(1, nx0.y)  XROW(2, nx0.z)  XROW(3, nx0.w) \
    XROW(4, nx1.x)  XROW(5, nx1.y)  XROW(6, nx1.z)  XROW(7, nx1.w) \
    XROW(8, nx2.x)  XROW(9, nx2.y)  XROW(10, nx2.z) XROW(11, nx2.w) \
    XROW(12, nx3.x) XROW(13, nx3.y) XROW(14, nx3.z) XROW(15, nx3.w) }

__global__ __launch_bounds__(512, 2)
void ChaoticLSTM_kernel(const float* __restrict__ x,  const float* __restrict__ Wi,
                        const float* __restrict__ Wh, const float* __restrict__ Bb,
                        float* __restrict__ out, unsigned long long* __restrict__ exch)
{
    const int bid   = blockIdx.x;
    const int xcd   = bid & 7;
    const int slotn = bid >> 3;
    const int b     = xcd * 8 + (slotn >> 2);  // batch element
    const int part  = slotn & 3;               // 64-unit chunk of H
    const int tid   = threadIdx.x;
    const int CG    = tid >> 3;                // hidden unit 0..63
    const int S     = tid & 7;                 // k-slice
    const int jglob = part * 64 + CG;
    const int wav   = tid >> 6;

    __shared__ __align__(16) float hp[4][2][64];   // [part][parity][unit]
    __shared__ int flg[4][2];                      // step tag of hp[p][par]

    // ---- weights into registers (all static indexing) ----
    float wh[128];   // [q<4][r<8][g<4]: h-row ((part+q)&3)*64 + S*8 + r
    float wi[64];    // [r<16][g<4]   : x-row S*16 + r
#pragma unroll
    for (int q = 0; q < 4; ++q) {
        const int psrc = (part + q) & 3;
#pragma unroll
        for (int r = 0; r < 8; ++r) {
            const float* p = Wh + (size_t)(psrc * 64 + S * 8 + r) * G4 + jglob;
            wh[q*32 + r*4 + 0] = p[0];   wh[q*32 + r*4 + 1] = p[256];
            wh[q*32 + r*4 + 2] = p[512]; wh[q*32 + r*4 + 3] = p[768];
        }
    }
#pragma unroll
    for (int r = 0; r < 16; ++r) {
        const float* p = Wi + (size_t)(S * 16 + r) * G4 + jglob;
        wi[r*4+0] = p[0]; wi[r*4+1] = p[256]; wi[r*4+2] = p[512]; wi[r*4+3] = p[768];
    }
    const float bb0 = Bb[jglob],       bb1 = Bb[256 + jglob];
    const float bb2 = Bb[512 + jglob], bb3 = Bb[768 + jglob];

    unsigned long long* __restrict__ exb = exch + (size_t)b * 512;
    const float* __restrict__ xrow = x + (size_t)b * SEQ * INPD + S * 16;

    // ---- roles ----
    const bool is_own = (S == 1);              // quad-role lane holding hn/cs
    const bool is_pw  = (wav >= 5);            // poller waves 5,6,7
    const int  pq     = is_pw ? (8 - wav) : 0; // wave7->chunk1, 6->2, 5->3
    const int  ppart  = (part + pq) & 3;
    const int  plane  = tid & 63;

    // ---- init ----
    if (tid < 512) ((float*)hp)[tid] = 0.f;
    if (tid < 8) ((int*)flg)[tid] = 0;
    if (tid < 64) {   // clear own exchange slots (both parities)
        __hip_atomic_store(&exb[part*64 + tid],       0ull, __ATOMIC_RELAXED, __HIP_MEMORY_SCOPE_AGENT);
        __hip_atomic_store(&exb[256 + part*64 + tid], 0ull, __ATOMIC_RELAXED, __HIP_MEMORY_SCOPE_AGENT);
    }
    float cs = 0.f, hn_keep = 0.f;

    // prologue x load (step 0)
    float4 nx0 = *(const float4*)(xrow);
    float4 nx1 = *(const float4*)(xrow + 4);
    float4 nx2 = *(const float4*)(xrow + 8);
    float4 nx3 = *(const float4*)(xrow + 12);
    __syncthreads();

    for (int st = 0; st < SEQ; ++st) {
        const int par = st & 1;

        // ---- poller waves: fetch partner h(st), publish via LDS flag ----
        if (is_pw && st >= 1) {
            unsigned long long* sp = exb + par * 256 + ppart * 64;
            unsigned long long v =
                __hip_atomic_load(&sp[plane], __ATOMIC_RELAXED, __HIP_MEMORY_SCOPE_AGENT);
            while ((unsigned)(v >> 32) != (unsigned)st)
                v = __hip_atomic_load(&sp[plane], __ATOMIC_RELAXED, __HIP_MEMORY_SCOPE_AGENT);
            hp[ppart][par][plane] = __uint_as_float((unsigned)v);
            if (plane == 0)
                __hip_atomic_store(&flg[ppart][par], st, __ATOMIC_RELEASE, __HIP_MEMORY_SCOPE_WORKGROUP);
        }

        // ---- chunk0: x-part + own part (no wait) ----
        float a0, a1, a2, a3;
        XPART_ALL;
        {
            const float4* hb = (const float4*)&hp[part][par][S * 8];
            float4 h0 = hb[0], h1 = hb[1];
            HCHUNK(0, h0, h1)
        }

        // ---- prefetch x for st+1 (consumed next step's chunk0) ----
        {
            const float* xp = xrow + (size_t)((st + 1 < SEQ) ? st + 1 : st) * INPD;
            nx0 = *(const float4*)(xp);
            nx1 = *(const float4*)(xp + 4);
            nx2 = *(const float4*)(xp + 8);
            nx3 = *(const float4*)(xp + 12);
        }

        // ---- chunks 1..3: remote parts behind LDS flags ----
#pragma unroll
        for (int q = 1; q < 4; ++q) {
            const int psrc = (part + q) & 3;
            if (st >= 1) {
                while (__hip_atomic_load(&flg[psrc][par], __ATOMIC_ACQUIRE,
                                         __HIP_MEMORY_SCOPE_WORKGROUP) != st) {}
            }
            const float4* hb = (const float4*)&hp[psrc][par][S * 8];
            float4 h0 = hb[0], h1 = hb[1];
            if (q == 1) { HCHUNK(1, h0, h1) }
            else if (q == 2) { HCHUNK(2, h0, h1) }
            else { HCHUNK(3, h0, h1) }
        }

        // ---- DPP allreduce over 8 S-lanes + bias ----
        a0 += dppf<DPP_XOR1>(a0); a1 += dppf<DPP_XOR1>(a1); a2 += dppf<DPP_XOR1>(a2); a3 += dppf<DPP_XOR1>(a3);
        a0 += dppf<DPP_XOR2>(a0); a1 += dppf<DPP_XOR2>(a1); a2 += dppf<DPP_XOR2>(a2); a3 += dppf<DPP_XOR2>(a3);
        a0 += dppf<DPP_HMIR>(a0); a1 += dppf<DPP_HMIR>(a1); a2 += dppf<DPP_HMIR>(a2); a3 += dppf<DPP_HMIR>(a3);
        a0 += bb0; a1 += bb1; a2 += bb2; a3 += bb3;

        // ---- branch-free quad-DPP cell update (valid on S==1 lane) ----
        const int r = S & 3;                   // 0:i 1:f 2:g 3:o
        float xs = (r & 1) ? ((r & 2) ? a3 : a1) : ((r & 2) ? a2 : a0);
        float kk = (r == 2) ? 2.f : 1.f;
        float e  = __expf(-kk * xs);
        float z  = __builtin_amdgcn_rcpf(1.f + e);
        z = fmaf(z, kk, 1.f - kk);             // g-role: 2*sig(2x)-1 = tanh
        float zg = dppf<DPP_XOR2>(z);          // r1 <- sig(o); r0 <- tanh(g)
        float p  = z * zg;                     // r0: i*g
        float pp = dppf<DPP_XOR1>(p);          // r1 <- i*g
        float cn = fmaf(z, cs, pp);            // r1: f*c + i*g
        float e2 = __expf(-2.f * cn);
        float tc = fmaf(__builtin_amdgcn_rcpf(1.f + e2), 2.f, -1.f);
        float hn = tc * zg;                    // r1: o * tanh(c')
        cs = cn;

        // ---- owner stores: exch FIRST (partners wait on it) ----
        if (is_own) {
            hn_keep = hn;
            if (st + 1 < SEQ) {
                unsigned long long w = ((unsigned long long)(st + 1) << 32)
                                     | (unsigned long long)__float_as_uint(hn);
                __hip_atomic_store(&exb[((st + 1) & 1) * 256 + jglob], w,
                                   __ATOMIC_RELAXED, __HIP_MEMORY_SCOPE_AGENT);
            }
            hp[part][(st + 1) & 1][CG] = hn;
            out[(size_t)(b * SEQ + st) * HID + jglob] = hn;
        }
        __syncthreads();   // parity buffer reuse + own-part availability
    }

    // ---- epilogue: ht, ct ----
    if (is_own) {
        size_t base = (size_t)BATCH * SEQ * HID;
        out[base + (size_t)b * HID + jglob] = hn_keep;
        out[base + (size_t)BATCH * HID + (size_t)b * HID + jglob] = cs;
    }
}

extern "C" void kernel_launch(void* const* d_in, const int* in_sizes, int n_in,
                              void* d_out, int out_size, void* d_ws, size_t ws_size,
                              hipStream_t stream) {
    const float* x  = (const float*)d_in[0];
    const float* Wi = (const float*)d_in[1];
    const float* Wh = (const float*)d_in[2];
    const float* B  = (const float*)d_in[3];
    float* out = (float*)d_out;
    unsigned long long* exch = (unsigned long long*)d_ws;   // 64*512*8 = 256 KB

    ChaoticLSTM_kernel<<<dim3(256), dim3(512), 0, stream>>>(x, Wi, Wh, B, out, exch);
}